// Round 19
// baseline (532.838 us; speedup 1.0000x reference)
//
#include <hip/hip_runtime.h>
#include <hip/hip_bf16.h>

#define LBUF 131072
#define TF   130048
#define TB   128

typedef short bf16x8 __attribute__((ext_vector_type(8)));
typedef float f32x4  __attribute__((ext_vector_type(4)));

__device__ __forceinline__ float ftanh(float x) {
  float ax = fminf(fabsf(x), 15.0f);
  float t  = __expf(2.0f * ax);
  float r  = 1.0f - 2.0f / (t + 1.0f);
  return copysignf(r, x);
}
__device__ __forceinline__ unsigned short b16(float f) {
  return __builtin_bit_cast(unsigned short, __float2bfloat16(f));
}
__device__ __forceinline__ float bf2f(unsigned short h) {
  return __builtin_bit_cast(float, ((unsigned)h) << 16);
}
__device__ __forceinline__ unsigned long long packhl2(float a, float b,
                                                      unsigned long long* lo) {
  unsigned short ha = b16(a), hb = b16(b);
  unsigned short la = b16(a - bf2f(ha)), lb = b16(b - bf2f(hb));
  *lo = (unsigned long long)la | ((unsigned long long)lb << 16);
  return (unsigned long long)ha | ((unsigned long long)hb << 16);
}

// Pre-pack all weights into split hi/lo bf16 planes (once per call).
// Conv planes use k' = tap*32 + c.
__global__ __launch_bounds__(256) void k_pack(
    const float* __restrict__ wf, const float* __restrict__ wg,
    const float* __restrict__ wr, const float* __restrict__ wsk,
    const float* __restrict__ w1, const float* __restrict__ w2,
    unsigned short* __restrict__ whp, unsigned short* __restrict__ w2p,
    unsigned short* __restrict__ w1p, unsigned short* __restrict__ w2fp)
{
  int i = blockIdx.x * 256 + threadIdx.x;
  if (i < 81920) {                       // conv weights: 20 x 4096
    int l = i >> 12, r = i & 4095;
    int m = r >> 6, k = r & 63;
    int c = k & 31, tap = k >> 5;
    float v = (m < 32) ? wf[l * 2048 + m * 64 + c * 2 + tap]
                       : wg[l * 2048 + (m - 32) * 64 + c * 2 + tap];
    unsigned short h = b16(v);
    whp[l * 8192 + m * 128 + k]      = h;
    whp[l * 8192 + m * 128 + 64 + k] = b16(v - bf2f(h));
  } else if (i < 112640) {               // 1x1 weights: 20 x 1536
    int t = i - 81920;
    int l = t / 1536, r = t - l * 1536;
    int m = r >> 5, o = r & 31;
    float v = (m < 32) ? wr[l * 1024 + m * 32 + o] : wsk[l * 512 + (m - 32) * 32 + o];
    unsigned short h = b16(v);
    w2p[l * 3072 + m * 64 + o]      = h;
    w2p[l * 3072 + m * 64 + 32 + o] = b16(v - bf2f(h));
  } else if (i < 116736) {               // W1: 4096
    int t = i - 112640;
    int q = t >> 4, k = t & 15;
    float v = w1[q * 16 + k];
    unsigned short h = b16(v);
    w1p[q * 32 + k]      = h;
    w1p[q * 32 + 16 + k] = b16(v - bf2f(h));
  } else {                               // W2: 65536
    int t = i - 116736;
    int q = t >> 8, k = t & 255;
    float v = w2[q * 256 + k];
    unsigned short h = b16(v);
    w2fp[q * 512 + k]       = h;
    w2fp[q * 512 + 256 + k] = b16(v - bf2f(h));
  }
}

// One dilated layer. TIME-MAJOR x[j][32], skip[j][16]. 512 thr, TB=128, 1 barrier.
__global__ __launch_bounds__(512) void k_layer(
    const float* __restrict__ xin, float* __restrict__ xout,
    float* __restrict__ skip,
    const unsigned* __restrict__ wsrc,        // packed conv w, 4096 u32
    const unsigned short* __restrict__ w2p,   // packed 1x1, [48][64]
    const float* __restrict__ rawin, const float* __restrict__ w_init,
    int Tn, int Told, int d, int pad, int off_s, int first, int writex)
{
  __shared__ alignas(16) char xs[32768];   // [128 col][256B: Lhi|Rhi|Llo|Rlo] ^((col&15)<<4)
  __shared__ alignas(16) char gs[16384];   // [128 col][128B: hi|lo] ^((col&7)<<4)
  __shared__ alignas(16) char wbuf[16384]; // [64 m][256B hi|lo] ^((m&15)<<4)

  int tid = threadIdx.x;
  int jb  = blockIdx.x * TB;
  int lane = tid & 63, w = tid >> 6;       // w 0..7
  int lr = lane & 15, lg = lane >> 4;

  // 1x1 fragments from packed global (L1/L2-hot)
  bf16x8 a2h[3], a2l[3];
#pragma unroll
  for (int mt = 0; mt < 3; ++mt) {
    int m = mt * 16 + lr;
    a2h[mt] = *(const bf16x8*)(w2p + m * 64 + lg * 8);
    a2l[mt] = *(const bf16x8*)(w2p + m * 64 + 32 + lg * 8);
  }

  // conv weights: pure u32 copies into swizzled LDS
  for (int i = tid; i < 4096; i += 512) {
    int m = i >> 6, j = i & 63;
    *(unsigned*)(wbuf + ((m * 256 + j * 4) ^ ((m & 15) << 4))) = wsrc[i];
  }
  // X staging: quad = 4 channels of one col (uniform bounds, aligned float4)
#pragma unroll
  for (int it = 0; it < 2; ++it) {
    int qi = tid + it * 512;          // 0..1023
    int col = qi >> 3, c4 = (qi & 7) * 4;
    int e0 = jb + col - pad, e1 = e0 + d;
    float4 L = {0.f, 0.f, 0.f, 0.f}, R = {0.f, 0.f, 0.f, 0.f};
    if (rawin) {
      float4 s = *(const float4*)&w_init[c4];
      if (e0 >= 0 && e0 < Told) {
        float v = rawin[e0];
        L = (float4){s.x * v, s.y * v, s.z * v, s.w * v};
      }
      if (e1 < Told) {
        float v = rawin[e1];
        R = (float4){s.x * v, s.y * v, s.z * v, s.w * v};
      }
    } else {
      if (e0 >= 0 && e0 < Told) L = *(const float4*)&xin[(size_t)e0 * 32 + c4];
      if (e1 < Told)            R = *(const float4*)&xin[(size_t)e1 * 32 + c4];
    }
    unsigned long long Lhi, Llo, Rhi, Rlo;
    {
      unsigned long long lo01, lo23, hi01, hi23;
      hi01 = packhl2(L.x, L.y, &lo01);
      hi23 = packhl2(L.z, L.w, &lo23);
      Lhi = hi01 | (hi23 << 32); Llo = lo01 | (lo23 << 32);
      hi01 = packhl2(R.x, R.y, &lo01);
      hi23 = packhl2(R.z, R.w, &lo23);
      Rhi = hi01 | (hi23 << 32); Rlo = lo01 | (lo23 << 32);
    }
    unsigned sw = (unsigned)(col & 15) << 4;
    int base = col * 256 + c4 * 2;
    *(unsigned long long*)(xs + ((base) ^ sw))       = Lhi;
    *(unsigned long long*)(xs + ((base + 64) ^ sw))  = Rhi;
    *(unsigned long long*)(xs + ((base + 128) ^ sw)) = Llo;
    *(unsigned long long*)(xs + ((base + 192) ^ sw)) = Rlo;
  }
  __syncthreads();

  int col = w * 16 + lr;                   // 0..127
  unsigned swx = (unsigned)lr << 4;

  // ---- GEMM1: K=64, 3-term split ----
  f32x4 acc1[4];
#pragma unroll
  for (int mt = 0; mt < 4; ++mt) acc1[mt] = (f32x4){0.f, 0.f, 0.f, 0.f};
#pragma unroll
  for (int ks = 0; ks < 2; ++ks) {
    bf16x8 bh = *(const bf16x8*)(xs + ((col * 256 + ks * 64 + lg * 16) ^ swx));
    bf16x8 bl = *(const bf16x8*)(xs + ((col * 256 + 128 + ks * 64 + lg * 16) ^ swx));
#pragma unroll
    for (int mt = 0; mt < 4; ++mt) {
      int row = mt * 16 + lr;
      bf16x8 ah = *(const bf16x8*)(wbuf + ((row * 256 + ks * 64 + lg * 16) ^ swx));
      bf16x8 al = *(const bf16x8*)(wbuf + ((row * 256 + 128 + ks * 64 + lg * 16) ^ swx));
      acc1[mt] = __builtin_amdgcn_mfma_f32_16x16x32_bf16(ah, bh, acc1[mt], 0, 0, 0);
      acc1[mt] = __builtin_amdgcn_mfma_f32_16x16x32_bf16(ah, bl, acc1[mt], 0, 0, 0);
      acc1[mt] = __builtin_amdgcn_mfma_f32_16x16x32_bf16(al, bh, acc1[mt], 0, 0, 0);
    }
  }

  // ---- gate -> gs split hi/lo (wave-local) ----
  unsigned swg = (unsigned)(col & 7) << 4;
#pragma unroll
  for (int t = 0; t < 2; ++t) {
    float g0 = ftanh(acc1[t][0]) * ftanh(acc1[t + 2][0]);
    float g1 = ftanh(acc1[t][1]) * ftanh(acc1[t + 2][1]);
    float g2 = ftanh(acc1[t][2]) * ftanh(acc1[t + 2][2]);
    float g3 = ftanh(acc1[t][3]) * ftanh(acc1[t + 2][3]);
    unsigned long long lo01, lo23;
    unsigned long long hi01 = packhl2(g0, g1, &lo01);
    unsigned long long hi23 = packhl2(g2, g3, &lo23);
    int ob = (t * 16 + lg * 4) * 2;
    *(unsigned long long*)(gs + ((col * 128 + ob) ^ swg))      = hi01 | (hi23 << 32);
    *(unsigned long long*)(gs + ((col * 128 + 64 + ob) ^ swg)) = lo01 | (lo23 << 32);
  }

  // ---- GEMM2: K=32, 3-term, A regs; wave-local B ----
  f32x4 acc2[3];
  {
    bf16x8 bgh = *(const bf16x8*)(gs + ((col * 128 + lg * 16) ^ swg));
    bf16x8 bgl = *(const bf16x8*)(gs + ((col * 128 + 64 + lg * 16) ^ swg));
#pragma unroll
    for (int mt = 0; mt < 3; ++mt) {
      f32x4 z = {0.f, 0.f, 0.f, 0.f};
      z = __builtin_amdgcn_mfma_f32_16x16x32_bf16(a2h[mt], bgh, z, 0, 0, 0);
      z = __builtin_amdgcn_mfma_f32_16x16x32_bf16(a2h[mt], bgl, z, 0, 0, 0);
      acc2[mt] = __builtin_amdgcn_mfma_f32_16x16x32_bf16(a2l[mt], bgh, z, 0, 0, 0);
    }
  }

  // ---- epilogue: direct register stores (time-major, aligned float4) ----
  int j = jb + col;
  if (writex && j < Tn) {
#pragma unroll
    for (int mt = 0; mt < 2; ++mt) {
      float4 v;
#pragma unroll
      for (int i = 0; i < 4; ++i) {
        int m = mt * 16 + lg * 4 + i;
        unsigned short xh = *(unsigned short*)(xs + ((col * 256 + 64 + m * 2) ^ swx));
        unsigned short xl = *(unsigned short*)(xs + ((col * 256 + 192 + m * 2) ^ swx));
        float r = acc2[mt][i] + (bf2f(xh) + bf2f(xl));
        if (i == 0) v.x = r; else if (i == 1) v.y = r; else if (i == 2) v.z = r; else v.w = r;
      }
      *(float4*)&xout[(size_t)j * 32 + mt * 16 + lg * 4] = v;
    }
  }
  int js = j - off_s;
  if (j < Tn && js >= 0) {
    float4 v = {acc2[2][0], acc2[2][1], acc2[2][2], acc2[2][3]};
    float* sp = skip + (size_t)js * 16 + lg * 4;
    if (first) {
      *(float4*)sp = v;
    } else {
      float4 o = *(const float4*)sp;
      o.x += v.x; o.y += v.y; o.z += v.z; o.w += v.w;
      *(float4*)sp = o;
    }
  }
}

// Fused final MLP: W2 chunks LDS double-buffered (stage kb+1 overlaps compute kb).
__global__ __launch_bounds__(256) void k_final(
    const float* __restrict__ skip,
    const unsigned short* __restrict__ w1p,
    const unsigned short* __restrict__ w2fp,
    float* __restrict__ out)
{
  __shared__ alignas(16) char smem[73728];
  char* sks = smem;             // [64 col][128B hi|lo] ^((col&7)<<4), 8KB
  char* h1s = smem + 8192;      // [64 col][512B hi] ^((col&31)<<4), 32KB
  char* w2b0 = smem + 40960;    // W2 chunk buf 0: [256 q][64B hi] ^((q&7)<<4), 16KB
  char* w2b1 = smem + 57344;    // W2 chunk buf 1
  float (*OutSq)[66] = (float (*)[66])&smem[0];  // 16.9KB, epilogue only (sks/h1s dead)

  int tid = threadIdx.x;
  int jb  = blockIdx.x * 64;
  int lane = tid & 63, w = tid >> 6;
  int lr = lane & 15, lg = lane >> 4;
  int col = w * 16 + lr;

  // skip staging: 1 aligned float4/thread (time-major), zero k>=16
  {
    int c = tid >> 2, k4 = (tid & 3) * 4;
    float4 v = *(const float4*)&skip[(size_t)(jb + c) * 16 + k4];
    v.x = fmaxf(v.x, 0.f); v.y = fmaxf(v.y, 0.f);
    v.z = fmaxf(v.z, 0.f); v.w = fmaxf(v.w, 0.f);
    unsigned long long lo01, lo23;
    unsigned long long hi01 = packhl2(v.x, v.y, &lo01);
    unsigned long long hi23 = packhl2(v.z, v.w, &lo23);
    unsigned sw = (unsigned)(c & 7) << 4;
    int base = c * 128 + k4 * 2;
    *(unsigned long long*)(sks + ((base) ^ sw))       = hi01 | (hi23 << 32);
    *(unsigned long long*)(sks + ((base + 64) ^ sw))  = lo01 | (lo23 << 32);
    *(unsigned long long*)(sks + ((base + 32) ^ sw))  = 0ull;
    *(unsigned long long*)(sks + ((base + 96) ^ sw))  = 0ull;
  }
  // stage W2 chunk 0 into buf0
  for (int i = tid; i < 1024; i += 256) {
    int q = i >> 2, part = i & 3;
    uint4 v = *(const uint4*)(w2fp + q * 512 + 0 * 32 + part * 8);
    *(uint4*)(w2b0 + ((q * 64 + part * 16) ^ ((q & 7) << 4))) = v;
  }
  __syncthreads();

  unsigned swk = (unsigned)(col & 7) << 4;
  unsigned swh = (unsigned)(col & 31) << 4;

  // GEMM1 -> H1 (wave-local handoff)
  {
    bf16x8 bh = *(const bf16x8*)(sks + ((col * 128 + lg * 16) ^ swk));
    bf16x8 bl = *(const bf16x8*)(sks + ((col * 128 + 64 + lg * 16) ^ swk));
#pragma unroll
    for (int mt = 0; mt < 16; ++mt) {
      bf16x8 ah = {0, 0, 0, 0, 0, 0, 0, 0};
      bf16x8 al = {0, 0, 0, 0, 0, 0, 0, 0};
      if (lg < 2) {
        int m = mt * 16 + lr;
        ah = *(const bf16x8*)(w1p + m * 32 + lg * 8);
        al = *(const bf16x8*)(w1p + m * 32 + 16 + lg * 8);
      }
      f32x4 z = {0.f, 0.f, 0.f, 0.f};
      z = __builtin_amdgcn_mfma_f32_16x16x32_bf16(ah, bh, z, 0, 0, 0);
      z = __builtin_amdgcn_mfma_f32_16x16x32_bf16(ah, bl, z, 0, 0, 0);
      z = __builtin_amdgcn_mfma_f32_16x16x32_bf16(al, bh, z, 0, 0, 0);
      int qb = (mt * 16 + lg * 4) * 2;
      unsigned p01 = (unsigned)b16(fmaxf(z[0], 0.f)) | ((unsigned)b16(fmaxf(z[1], 0.f)) << 16);
      unsigned p23 = (unsigned)b16(fmaxf(z[2], 0.f)) | ((unsigned)b16(fmaxf(z[3], 0.f)) << 16);
      *(unsigned*)(h1s + ((col * 512 + qb) ^ swh))     = p01;
      *(unsigned*)(h1s + ((col * 512 + qb + 4) ^ swh)) = p23;
    }
  }

  // GEMM2: 8 chunks, double-buffered staging, 1 barrier/chunk
  f32x4 acco[16];
#pragma unroll
  for (int mt = 0; mt < 16; ++mt) acco[mt] = (f32x4){0.f, 0.f, 0.f, 0.f};

#pragma unroll
  for (int kb = 0; kb < 8; ++kb) {
    char* cur = (kb & 1) ? w2b1 : w2b0;
    char* nxt = (kb & 1) ? w2b0 : w2b1;
    if (kb < 7) {
      for (int i = tid; i < 1024; i += 256) {
        int q = i >> 2, part = i & 3;
        uint4 v = *(const uint4*)(w2fp + q * 512 + (kb + 1) * 32 + part * 8);
        *(uint4*)(nxt + ((q * 64 + part * 16) ^ ((q & 7) << 4))) = v;
      }
    }
    bf16x8 bh = *(const bf16x8*)(h1s + ((col * 512 + kb * 64 + lg * 16) ^ swh));
#pragma unroll
    for (int mt = 0; mt < 16; ++mt) {
      int row = mt * 16 + lr;
      bf16x8 ah = *(const bf16x8*)(cur + ((row * 64 + lg * 16) ^ ((row & 7) << 4)));
      acco[mt] = __builtin_amdgcn_mfma_f32_16x16x32_bf16(ah, bh, acco[mt], 0, 0, 0);
    }
    __syncthreads();   // stage kb+1 done; compute kb done (buf reusable at kb+2)
  }

  // epilogue: 4 quarter-q passes through OutSq
#pragma unroll
  for (int p = 0; p < 4; ++p) {
#pragma unroll
    for (int mq = 0; mq < 4; ++mq)
#pragma unroll
      for (int i = 0; i < 4; ++i)
        OutSq[mq * 16 + lg * 4 + i][col] = acco[p * 4 + mq][i];
    __syncthreads();
    int r = tid >> 2, cb = (tid & 3) * 16;
    size_t base = (size_t)(p * 64 + r) * TF + jb + cb;
#pragma unroll
    for (int v = 0; v < 4; ++v)
      *(float4*)&out[base + v * 4] = *(float4*)&OutSq[r][cb + v * 4];
    __syncthreads();
  }
}

extern "C" void kernel_launch(void* const* d_in, const int* in_sizes, int n_in,
                              void* d_out, int out_size, void* d_ws, size_t ws_size,
                              hipStream_t stream) {
  const float* x_in     = (const float*)d_in[0];
  const float* w_init   = (const float*)d_in[1];
  const float* w_filter = (const float*)d_in[2];
  const float* w_gate   = (const float*)d_in[3];
  const float* w_res    = (const float*)d_in[4];
  const float* w_skip   = (const float*)d_in[5];
  const float* w_f1     = (const float*)d_in[6];
  const float* w_f2     = (const float*)d_in[7];
  float* out = (float*)d_out;

  float* xa    = (float*)d_ws;                    // time-major [LBUF][32]
  float* xb    = xa + 32 * (size_t)LBUF;
  float* skipb = xb + 32 * (size_t)LBUF;          // time-major [TF][16]
  unsigned short* whp  = (unsigned short*)(skipb + 16 * (size_t)TF);
  unsigned short* w2p  = whp + 20 * 8192;
  unsigned short* w1p  = w2p + 20 * 3072;
  unsigned short* w2fp = w1p + 8192;

  k_pack<<<712, 256, 0, stream>>>(w_filter, w_gate, w_res, w_skip, w_f1, w_f2,
                                  whp, w2p, w1p, w2fp);

  int T = LBUF;
  for (int idx = 0; idx < 20; ++idx) {
    int d    = 1 << (idx % 10);
    int pad  = (d - (T % d)) % d;
    int Tn   = T + pad - d;
    int offs = Tn - TF;
    k_layer<<<(Tn + TB - 1) / TB, 512, 0, stream>>>(
        xa, xb, skipb,
        (const unsigned*)(whp + (size_t)idx * 8192), w2p + (size_t)idx * 3072,
        (idx == 0) ? x_in : nullptr, w_init,
        Tn, T, d, pad, offs, (idx == 0) ? 1 : 0, (idx == 19) ? 0 : 1);
    float* t = xa; xa = xb; xb = t;
    T = Tn;
  }

  k_final<<<TF / 64, 256, 0, stream>>>(skipb, w1p, w2fp, out);
}

// Round 20
// 486.683 us; speedup vs baseline: 1.0948x; 1.0948x over previous
//
#include <hip/hip_runtime.h>
#include <hip/hip_bf16.h>

#define LBUF 131072
#define TF   130048
#define TB   64

typedef short bf16x8 __attribute__((ext_vector_type(8)));
typedef float f32x4  __attribute__((ext_vector_type(4)));

__device__ __forceinline__ float ftanh(float x) {
  float ax = fminf(fabsf(x), 15.0f);
  float t  = __expf(2.0f * ax);
  float r  = 1.0f - 2.0f / (t + 1.0f);
  return copysignf(r, x);
}
__device__ __forceinline__ unsigned short b16(float f) {
  return __builtin_bit_cast(unsigned short, __float2bfloat16(f));
}
__device__ __forceinline__ float bf2f(unsigned short h) {
  return __builtin_bit_cast(float, ((unsigned)h) << 16);
}
__device__ __forceinline__ unsigned long long packhl2(float a, float b,
                                                      unsigned long long* lo) {
  unsigned short ha = b16(a), hb = b16(b);
  unsigned short la = b16(a - bf2f(ha)), lb = b16(b - bf2f(hb));
  *lo = (unsigned long long)la | ((unsigned long long)lb << 16);
  return (unsigned long long)ha | ((unsigned long long)hb << 16);
}

// Pre-pack all weights into split hi/lo bf16 planes (once per call).
// Conv planes use k' = tap*32 + c.
__global__ __launch_bounds__(256) void k_pack(
    const float* __restrict__ wf, const float* __restrict__ wg,
    const float* __restrict__ wr, const float* __restrict__ wsk,
    const float* __restrict__ w1, const float* __restrict__ w2,
    unsigned short* __restrict__ whp, unsigned short* __restrict__ w2p,
    unsigned short* __restrict__ w1p, unsigned short* __restrict__ w2fp)
{
  int i = blockIdx.x * 256 + threadIdx.x;
  if (i < 81920) {                       // conv weights: 20 x 4096
    int l = i >> 12, r = i & 4095;
    int m = r >> 6, k = r & 63;
    int c = k & 31, tap = k >> 5;
    float v = (m < 32) ? wf[l * 2048 + m * 64 + c * 2 + tap]
                       : wg[l * 2048 + (m - 32) * 64 + c * 2 + tap];
    unsigned short h = b16(v);
    whp[l * 8192 + m * 128 + k]      = h;
    whp[l * 8192 + m * 128 + 64 + k] = b16(v - bf2f(h));
  } else if (i < 112640) {               // 1x1 weights: 20 x 1536
    int t = i - 81920;
    int l = t / 1536, r = t - l * 1536;
    int m = r >> 5, o = r & 31;
    float v = (m < 32) ? wr[l * 1024 + m * 32 + o] : wsk[l * 512 + (m - 32) * 32 + o];
    unsigned short h = b16(v);
    w2p[l * 3072 + m * 64 + o]      = h;
    w2p[l * 3072 + m * 64 + 32 + o] = b16(v - bf2f(h));
  } else if (i < 116736) {               // W1: 4096
    int t = i - 112640;
    int q = t >> 4, k = t & 15;
    float v = w1[q * 16 + k];
    unsigned short h = b16(v);
    w1p[q * 32 + k]      = h;
    w1p[q * 32 + 16 + k] = b16(v - bf2f(h));
  } else {                               // W2: 65536
    int t = i - 116736;
    int q = t >> 8, k = t & 255;
    float v = w2[q * 256 + k];
    unsigned short h = b16(v);
    w2fp[q * 512 + k]       = h;
    w2fp[q * 512 + 256 + k] = b16(v - bf2f(h));
  }
}

// One dilated layer. TIME-MAJOR x[j][32], skip[j][16]. R18 structure (measured best)
// + bijective XCD-chunked block swizzle (m204): left/right tap reuse lands same-XCD L2.
__global__ __launch_bounds__(256) void k_layer(
    const float* __restrict__ xin, float* __restrict__ xout,
    float* __restrict__ skip,
    const unsigned* __restrict__ wsrc,        // packed conv w, 4096 u32
    const unsigned short* __restrict__ w2p,   // packed 1x1, [48][64]
    const float* __restrict__ rawin, const float* __restrict__ w_init,
    int Tn, int Told, int d, int pad, int off_s, int first, int writex)
{
  __shared__ alignas(16) char xs[16384];   // [64 col][256B: Lhi|Rhi|Llo|Rlo] ^((col&15)<<4)
  __shared__ alignas(16) char gs[8192];    // [64 col][128B: hi|lo] ^((col&7)<<4)
  __shared__ alignas(16) char wbuf[16384]; // [64 m][256B hi|lo] ^((m&15)<<4)

  int tid = threadIdx.x;
  // XCD-chunked bijective swizzle (8 XCDs): contiguous grid chunk per XCD.
  int nwg = gridDim.x, orig = blockIdx.x;
  int xcd = orig & 7, qc = nwg >> 3, rc = nwg & 7;
  int bid = ((xcd < rc) ? xcd * (qc + 1) : rc * (qc + 1) + (xcd - rc) * qc) + (orig >> 3);
  int jb  = bid * TB;
  int lane = tid & 63, w = tid >> 6;
  int lr = lane & 15, lg = lane >> 4;

  // 1x1 fragments from packed global (L1/L2-hot)
  bf16x8 a2h[3], a2l[3];
#pragma unroll
  for (int mt = 0; mt < 3; ++mt) {
    int m = mt * 16 + lr;
    a2h[mt] = *(const bf16x8*)(w2p + m * 64 + lg * 8);
    a2l[mt] = *(const bf16x8*)(w2p + m * 64 + 32 + lg * 8);
  }

  // conv weights: pure u32 copies into swizzled LDS
  for (int i = tid; i < 4096; i += 256) {
    int m = i >> 6, j = i & 63;
    *(unsigned*)(wbuf + ((m * 256 + j * 4) ^ ((m & 15) << 4))) = wsrc[i];
  }
  // X staging: quad = 4 channels of one col (uniform bounds, aligned float4)
#pragma unroll
  for (int it = 0; it < 2; ++it) {
    int qi = tid + it * 256;          // 0..511
    int col = qi >> 3, c4 = (qi & 7) * 4;
    int e0 = jb + col - pad, e1 = e0 + d;
    float4 L = {0.f, 0.f, 0.f, 0.f}, R = {0.f, 0.f, 0.f, 0.f};
    if (rawin) {
      float4 s = *(const float4*)&w_init[c4];
      if (e0 >= 0 && e0 < Told) {
        float v = rawin[e0];
        L = (float4){s.x * v, s.y * v, s.z * v, s.w * v};
      }
      if (e1 < Told) {
        float v = rawin[e1];
        R = (float4){s.x * v, s.y * v, s.z * v, s.w * v};
      }
    } else {
      if (e0 >= 0 && e0 < Told) L = *(const float4*)&xin[(size_t)e0 * 32 + c4];
      if (e1 < Told)            R = *(const float4*)&xin[(size_t)e1 * 32 + c4];
    }
    unsigned long long Lhi, Llo, Rhi, Rlo;
    {
      unsigned long long lo01, lo23, hi01, hi23;
      hi01 = packhl2(L.x, L.y, &lo01);
      hi23 = packhl2(L.z, L.w, &lo23);
      Lhi = hi01 | (hi23 << 32); Llo = lo01 | (lo23 << 32);
      hi01 = packhl2(R.x, R.y, &lo01);
      hi23 = packhl2(R.z, R.w, &lo23);
      Rhi = hi01 | (hi23 << 32); Rlo = lo01 | (lo23 << 32);
    }
    unsigned sw = (unsigned)(col & 15) << 4;
    int base = col * 256 + c4 * 2;
    *(unsigned long long*)(xs + ((base) ^ sw))       = Lhi;
    *(unsigned long long*)(xs + ((base + 64) ^ sw))  = Rhi;
    *(unsigned long long*)(xs + ((base + 128) ^ sw)) = Llo;
    *(unsigned long long*)(xs + ((base + 192) ^ sw)) = Rlo;
  }
  __syncthreads();

  int col = w * 16 + lr;
  unsigned swx = (unsigned)lr << 4;

  // ---- GEMM1: K=64, 3-term split ----
  f32x4 acc1[4];
#pragma unroll
  for (int mt = 0; mt < 4; ++mt) acc1[mt] = (f32x4){0.f, 0.f, 0.f, 0.f};
#pragma unroll
  for (int ks = 0; ks < 2; ++ks) {
    bf16x8 bh = *(const bf16x8*)(xs + ((col * 256 + ks * 64 + lg * 16) ^ swx));
    bf16x8 bl = *(const bf16x8*)(xs + ((col * 256 + 128 + ks * 64 + lg * 16) ^ swx));
#pragma unroll
    for (int mt = 0; mt < 4; ++mt) {
      int row = mt * 16 + lr;
      bf16x8 ah = *(const bf16x8*)(wbuf + ((row * 256 + ks * 64 + lg * 16) ^ swx));
      bf16x8 al = *(const bf16x8*)(wbuf + ((row * 256 + 128 + ks * 64 + lg * 16) ^ swx));
      acc1[mt] = __builtin_amdgcn_mfma_f32_16x16x32_bf16(ah, bh, acc1[mt], 0, 0, 0);
      acc1[mt] = __builtin_amdgcn_mfma_f32_16x16x32_bf16(ah, bl, acc1[mt], 0, 0, 0);
      acc1[mt] = __builtin_amdgcn_mfma_f32_16x16x32_bf16(al, bh, acc1[mt], 0, 0, 0);
    }
  }

  // ---- gate -> gs split hi/lo (wave-local) ----
  unsigned swg = (unsigned)(col & 7) << 4;
#pragma unroll
  for (int t = 0; t < 2; ++t) {
    float g0 = ftanh(acc1[t][0]) * ftanh(acc1[t + 2][0]);
    float g1 = ftanh(acc1[t][1]) * ftanh(acc1[t + 2][1]);
    float g2 = ftanh(acc1[t][2]) * ftanh(acc1[t + 2][2]);
    float g3 = ftanh(acc1[t][3]) * ftanh(acc1[t + 2][3]);
    unsigned long long lo01, lo23;
    unsigned long long hi01 = packhl2(g0, g1, &lo01);
    unsigned long long hi23 = packhl2(g2, g3, &lo23);
    int ob = (t * 16 + lg * 4) * 2;
    *(unsigned long long*)(gs + ((col * 128 + ob) ^ swg))      = hi01 | (hi23 << 32);
    *(unsigned long long*)(gs + ((col * 128 + 64 + ob) ^ swg)) = lo01 | (lo23 << 32);
  }

  // ---- GEMM2: K=32, 3-term, A regs; wave-local B ----
  f32x4 acc2[3];
  {
    bf16x8 bgh = *(const bf16x8*)(gs + ((col * 128 + lg * 16) ^ swg));
    bf16x8 bgl = *(const bf16x8*)(gs + ((col * 128 + 64 + lg * 16) ^ swg));
#pragma unroll
    for (int mt = 0; mt < 3; ++mt) {
      f32x4 z = {0.f, 0.f, 0.f, 0.f};
      z = __builtin_amdgcn_mfma_f32_16x16x32_bf16(a2h[mt], bgh, z, 0, 0, 0);
      z = __builtin_amdgcn_mfma_f32_16x16x32_bf16(a2h[mt], bgl, z, 0, 0, 0);
      acc2[mt] = __builtin_amdgcn_mfma_f32_16x16x32_bf16(a2l[mt], bgh, z, 0, 0, 0);
    }
  }

  // ---- epilogue: direct register stores (time-major, aligned float4) ----
  int j = jb + col;
  if (writex && j < Tn) {
#pragma unroll
    for (int mt = 0; mt < 2; ++mt) {
      float4 v;
#pragma unroll
      for (int i = 0; i < 4; ++i) {
        int m = mt * 16 + lg * 4 + i;
        unsigned short xh = *(unsigned short*)(xs + ((col * 256 + 64 + m * 2) ^ swx));
        unsigned short xl = *(unsigned short*)(xs + ((col * 256 + 192 + m * 2) ^ swx));
        float r = acc2[mt][i] + (bf2f(xh) + bf2f(xl));
        if (i == 0) v.x = r; else if (i == 1) v.y = r; else if (i == 2) v.z = r; else v.w = r;
      }
      *(float4*)&xout[(size_t)j * 32 + mt * 16 + lg * 4] = v;
    }
  }
  int js = j - off_s;
  if (j < Tn && js >= 0) {
    float4 v = {acc2[2][0], acc2[2][1], acc2[2][2], acc2[2][3]};
    float* sp = skip + (size_t)js * 16 + lg * 4;
    if (first) {
      *(float4*)sp = v;
    } else {
      float4 o = *(const float4*)sp;
      o.x += v.x; o.y += v.y; o.z += v.z; o.w += v.w;
      *(float4*)sp = o;
    }
  }
}

// Fused final MLP (R18 version exact — measured 96 us; 48KB LDS, 3 blocks/CU).
__global__ __launch_bounds__(256) void k_final(
    const float* __restrict__ skip,
    const unsigned short* __restrict__ w1p,
    const unsigned short* __restrict__ w2fp,
    float* __restrict__ out)
{
  __shared__ alignas(16) char smem[49152];
  char* sks = smem;             // [64 col][128B hi|lo] ^((col&7)<<4), 8KB
  char* w2s = smem;             // [256 q][64B hi] ^((q&7)<<4), 16KB (aliases sks)
  char* h1s = smem + 16384;     // [64 col][512B hi] ^((col&31)<<4), 32KB
  float (*OutSq)[66] = (float (*)[66])&smem[0];

  int tid = threadIdx.x;
  int jb  = blockIdx.x * 64;
  int lane = tid & 63, w = tid >> 6;
  int lr = lane & 15, lg = lane >> 4;
  int col = w * 16 + lr;

  // skip staging: 1 aligned float4/thread (time-major), zero k>=16
  {
    int c = tid >> 2, k4 = (tid & 3) * 4;
    float4 v = *(const float4*)&skip[(size_t)(jb + c) * 16 + k4];
    v.x = fmaxf(v.x, 0.f); v.y = fmaxf(v.y, 0.f);
    v.z = fmaxf(v.z, 0.f); v.w = fmaxf(v.w, 0.f);
    unsigned long long lo01, lo23;
    unsigned long long hi01 = packhl2(v.x, v.y, &lo01);
    unsigned long long hi23 = packhl2(v.z, v.w, &lo23);
    unsigned sw = (unsigned)(c & 7) << 4;
    int base = c * 128 + k4 * 2;
    *(unsigned long long*)(sks + ((base) ^ sw))       = hi01 | (hi23 << 32);
    *(unsigned long long*)(sks + ((base + 64) ^ sw))  = lo01 | (lo23 << 32);
    *(unsigned long long*)(sks + ((base + 32) ^ sw))  = 0ull;
    *(unsigned long long*)(sks + ((base + 96) ^ sw))  = 0ull;
  }
  __syncthreads();

  unsigned swk = (unsigned)(col & 7) << 4;
  unsigned swh = (unsigned)(col & 31) << 4;

  // GEMM1 -> H1 (wave-local handoff)
  {
    bf16x8 bh = *(const bf16x8*)(sks + ((col * 128 + lg * 16) ^ swk));
    bf16x8 bl = *(const bf16x8*)(sks + ((col * 128 + 64 + lg * 16) ^ swk));
#pragma unroll
    for (int mt = 0; mt < 16; ++mt) {
      bf16x8 ah = {0, 0, 0, 0, 0, 0, 0, 0};
      bf16x8 al = {0, 0, 0, 0, 0, 0, 0, 0};
      if (lg < 2) {
        int m = mt * 16 + lr;
        ah = *(const bf16x8*)(w1p + m * 32 + lg * 8);
        al = *(const bf16x8*)(w1p + m * 32 + 16 + lg * 8);
      }
      f32x4 z = {0.f, 0.f, 0.f, 0.f};
      z = __builtin_amdgcn_mfma_f32_16x16x32_bf16(ah, bh, z, 0, 0, 0);
      z = __builtin_amdgcn_mfma_f32_16x16x32_bf16(ah, bl, z, 0, 0, 0);
      z = __builtin_amdgcn_mfma_f32_16x16x32_bf16(al, bh, z, 0, 0, 0);
      int qb = (mt * 16 + lg * 4) * 2;
      unsigned p01 = (unsigned)b16(fmaxf(z[0], 0.f)) | ((unsigned)b16(fmaxf(z[1], 0.f)) << 16);
      unsigned p23 = (unsigned)b16(fmaxf(z[2], 0.f)) | ((unsigned)b16(fmaxf(z[3], 0.f)) << 16);
      *(unsigned*)(h1s + ((col * 512 + qb) ^ swh))     = p01;
      *(unsigned*)(h1s + ((col * 512 + qb + 4) ^ swh)) = p23;
    }
  }

  // GEMM2: K=256 in 8 chunks; W2 hi-only staged into w2s (aliases sks)
  f32x4 acco[16];
#pragma unroll
  for (int mt = 0; mt < 16; ++mt) acco[mt] = (f32x4){0.f, 0.f, 0.f, 0.f};

  for (int kb = 0; kb < 8; ++kb) {
    __syncthreads();
    for (int i = tid; i < 1024; i += 256) {
      int q = i >> 2, part = i & 3;
      uint4 v = *(const uint4*)(w2fp + q * 512 + kb * 32 + part * 8);
      *(uint4*)(w2s + ((q * 64 + part * 16) ^ ((q & 7) << 4))) = v;
    }
    __syncthreads();
    bf16x8 bh = *(const bf16x8*)(h1s + ((col * 512 + kb * 64 + lg * 16) ^ swh));
#pragma unroll
    for (int mt = 0; mt < 16; ++mt) {
      int row = mt * 16 + lr;
      bf16x8 ah = *(const bf16x8*)(w2s + ((row * 64 + lg * 16) ^ ((row & 7) << 4)));
      acco[mt] = __builtin_amdgcn_mfma_f32_16x16x32_bf16(ah, bh, acco[mt], 0, 0, 0);
    }
  }

#pragma unroll
  for (int p = 0; p < 4; ++p) {
    __syncthreads();
#pragma unroll
    for (int mq = 0; mq < 4; ++mq)
#pragma unroll
      for (int i = 0; i < 4; ++i)
        OutSq[mq * 16 + lg * 4 + i][col] = acco[p * 4 + mq][i];
    __syncthreads();
    int r = tid >> 2, cb = (tid & 3) * 16;
    size_t base = (size_t)(p * 64 + r) * TF + jb + cb;
#pragma unroll
    for (int v = 0; v < 4; ++v)
      *(float4*)&out[base + v * 4] = *(float4*)&OutSq[r][cb + v * 4];
  }
}

extern "C" void kernel_launch(void* const* d_in, const int* in_sizes, int n_in,
                              void* d_out, int out_size, void* d_ws, size_t ws_size,
                              hipStream_t stream) {
  const float* x_in     = (const float*)d_in[0];
  const float* w_init   = (const float*)d_in[1];
  const float* w_filter = (const float*)d_in[2];
  const float* w_gate   = (const float*)d_in[3];
  const float* w_res    = (const float*)d_in[4];
  const float* w_skip   = (const float*)d_in[5];
  const float* w_f1     = (const float*)d_in[6];
  const float* w_f2     = (const float*)d_in[7];
  float* out = (float*)d_out;

  float* xa    = (float*)d_ws;                    // time-major [LBUF][32]
  float* xb    = xa + 32 * (size_t)LBUF;
  float* skipb = xb + 32 * (size_t)LBUF;          // time-major [TF][16]
  unsigned short* whp  = (unsigned short*)(skipb + 16 * (size_t)TF);
  unsigned short* w2p  = whp + 20 * 8192;
  unsigned short* w1p  = w2p + 20 * 3072;
  unsigned short* w2fp = w1p + 8192;

  k_pack<<<712, 256, 0, stream>>>(w_filter, w_gate, w_res, w_skip, w_f1, w_f2,
                                  whp, w2p, w1p, w2fp);

  int T = LBUF;
  for (int idx = 0; idx < 20; ++idx) {
    int d    = 1 << (idx % 10);
    int pad  = (d - (T % d)) % d;
    int Tn   = T + pad - d;
    int offs = Tn - TF;
    k_layer<<<(Tn + TB - 1) / TB, 256, 0, stream>>>(
        xa, xb, skipb,
        (const unsigned*)(whp + (size_t)idx * 8192), w2p + (size_t)idx * 3072,
        (idx == 0) ? x_in : nullptr, w_init,
        Tn, T, d, pad, offs, (idx == 0) ? 1 : 0, (idx == 19) ? 0 : 1);
    float* t = xa; xa = xb; xb = t;
    T = Tn;
  }

  k_final<<<TF / 64, 256, 0, stream>>>(skipb, w1p, w2fp, out);
}

// Round 21
// 470.877 us; speedup vs baseline: 1.1316x; 1.0336x over previous
//
#include <hip/hip_runtime.h>
#include <hip/hip_bf16.h>

#define LBUF 131072
#define TF   130048
#define TB   64

typedef short bf16x8 __attribute__((ext_vector_type(8)));
typedef float f32x4  __attribute__((ext_vector_type(4)));

__device__ __forceinline__ float ftanh(float x) {
  float ax = fminf(fabsf(x), 15.0f);
  float t  = __expf(2.0f * ax);
  float r  = 1.0f - 2.0f / (t + 1.0f);
  return copysignf(r, x);
}
__device__ __forceinline__ unsigned short b16(float f) {
  return __builtin_bit_cast(unsigned short, __float2bfloat16(f));
}
__device__ __forceinline__ float bf2f(unsigned short h) {
  return __builtin_bit_cast(float, ((unsigned)h) << 16);
}
__device__ __forceinline__ unsigned long long packhl2(float a, float b,
                                                      unsigned long long* lo) {
  unsigned short ha = b16(a), hb = b16(b);
  unsigned short la = b16(a - bf2f(ha)), lb = b16(b - bf2f(hb));
  *lo = (unsigned long long)la | ((unsigned long long)lb << 16);
  return (unsigned long long)ha | ((unsigned long long)hb << 16);
}

// Pre-pack all weights into split hi/lo bf16 planes (once per call).
// Conv planes use k' = tap*32 + c.
__global__ __launch_bounds__(256) void k_pack(
    const float* __restrict__ wf, const float* __restrict__ wg,
    const float* __restrict__ wr, const float* __restrict__ wsk,
    const float* __restrict__ w1, const float* __restrict__ w2,
    unsigned short* __restrict__ whp, unsigned short* __restrict__ w2p,
    unsigned short* __restrict__ w1p, unsigned short* __restrict__ w2fp)
{
  int i = blockIdx.x * 256 + threadIdx.x;
  if (i < 81920) {                       // conv weights: 20 x 4096
    int l = i >> 12, r = i & 4095;
    int m = r >> 6, k = r & 63;
    int c = k & 31, tap = k >> 5;
    float v = (m < 32) ? wf[l * 2048 + m * 64 + c * 2 + tap]
                       : wg[l * 2048 + (m - 32) * 64 + c * 2 + tap];
    unsigned short h = b16(v);
    whp[l * 8192 + m * 128 + k]      = h;
    whp[l * 8192 + m * 128 + 64 + k] = b16(v - bf2f(h));
  } else if (i < 112640) {               // 1x1 weights: 20 x 1536
    int t = i - 81920;
    int l = t / 1536, r = t - l * 1536;
    int m = r >> 5, o = r & 31;
    float v = (m < 32) ? wr[l * 1024 + m * 32 + o] : wsk[l * 512 + (m - 32) * 32 + o];
    unsigned short h = b16(v);
    w2p[l * 3072 + m * 64 + o]      = h;
    w2p[l * 3072 + m * 64 + 32 + o] = b16(v - bf2f(h));
  } else if (i < 116736) {               // W1: 4096
    int t = i - 112640;
    int q = t >> 4, k = t & 15;
    float v = w1[q * 16 + k];
    unsigned short h = b16(v);
    w1p[q * 32 + k]      = h;
    w1p[q * 32 + 16 + k] = b16(v - bf2f(h));
  } else {                               // W2: 65536
    int t = i - 116736;
    int q = t >> 8, k = t & 255;
    float v = w2[q * 256 + k];
    unsigned short h = b16(v);
    w2fp[q * 512 + k]       = h;
    w2fp[q * 512 + 256 + k] = b16(v - bf2f(h));
  }
}

// One dilated layer. TIME-MAJOR x[j][32], skip[j][16]. R18 structure + XCD swizzle
// (R20 measured best — unchanged).
__global__ __launch_bounds__(256) void k_layer(
    const float* __restrict__ xin, float* __restrict__ xout,
    float* __restrict__ skip,
    const unsigned* __restrict__ wsrc,        // packed conv w, 4096 u32
    const unsigned short* __restrict__ w2p,   // packed 1x1, [48][64]
    const float* __restrict__ rawin, const float* __restrict__ w_init,
    int Tn, int Told, int d, int pad, int off_s, int first, int writex)
{
  __shared__ alignas(16) char xs[16384];   // [64 col][256B: Lhi|Rhi|Llo|Rlo] ^((col&15)<<4)
  __shared__ alignas(16) char gs[8192];    // [64 col][128B: hi|lo] ^((col&7)<<4)
  __shared__ alignas(16) char wbuf[16384]; // [64 m][256B hi|lo] ^((m&15)<<4)

  int tid = threadIdx.x;
  // XCD-chunked bijective swizzle (8 XCDs)
  int nwg = gridDim.x, orig = blockIdx.x;
  int xcd = orig & 7, qc = nwg >> 3, rc = nwg & 7;
  int bid = ((xcd < rc) ? xcd * (qc + 1) : rc * (qc + 1) + (xcd - rc) * qc) + (orig >> 3);
  int jb  = bid * TB;
  int lane = tid & 63, w = tid >> 6;
  int lr = lane & 15, lg = lane >> 4;

  bf16x8 a2h[3], a2l[3];
#pragma unroll
  for (int mt = 0; mt < 3; ++mt) {
    int m = mt * 16 + lr;
    a2h[mt] = *(const bf16x8*)(w2p + m * 64 + lg * 8);
    a2l[mt] = *(const bf16x8*)(w2p + m * 64 + 32 + lg * 8);
  }

  for (int i = tid; i < 4096; i += 256) {
    int m = i >> 6, j = i & 63;
    *(unsigned*)(wbuf + ((m * 256 + j * 4) ^ ((m & 15) << 4))) = wsrc[i];
  }
#pragma unroll
  for (int it = 0; it < 2; ++it) {
    int qi = tid + it * 256;
    int col = qi >> 3, c4 = (qi & 7) * 4;
    int e0 = jb + col - pad, e1 = e0 + d;
    float4 L = {0.f, 0.f, 0.f, 0.f}, R = {0.f, 0.f, 0.f, 0.f};
    if (rawin) {
      float4 s = *(const float4*)&w_init[c4];
      if (e0 >= 0 && e0 < Told) {
        float v = rawin[e0];
        L = (float4){s.x * v, s.y * v, s.z * v, s.w * v};
      }
      if (e1 < Told) {
        float v = rawin[e1];
        R = (float4){s.x * v, s.y * v, s.z * v, s.w * v};
      }
    } else {
      if (e0 >= 0 && e0 < Told) L = *(const float4*)&xin[(size_t)e0 * 32 + c4];
      if (e1 < Told)            R = *(const float4*)&xin[(size_t)e1 * 32 + c4];
    }
    unsigned long long Lhi, Llo, Rhi, Rlo;
    {
      unsigned long long lo01, lo23, hi01, hi23;
      hi01 = packhl2(L.x, L.y, &lo01);
      hi23 = packhl2(L.z, L.w, &lo23);
      Lhi = hi01 | (hi23 << 32); Llo = lo01 | (lo23 << 32);
      hi01 = packhl2(R.x, R.y, &lo01);
      hi23 = packhl2(R.z, R.w, &lo23);
      Rhi = hi01 | (hi23 << 32); Rlo = lo01 | (lo23 << 32);
    }
    unsigned sw = (unsigned)(col & 15) << 4;
    int base = col * 256 + c4 * 2;
    *(unsigned long long*)(xs + ((base) ^ sw))       = Lhi;
    *(unsigned long long*)(xs + ((base + 64) ^ sw))  = Rhi;
    *(unsigned long long*)(xs + ((base + 128) ^ sw)) = Llo;
    *(unsigned long long*)(xs + ((base + 192) ^ sw)) = Rlo;
  }
  __syncthreads();

  int col = w * 16 + lr;
  unsigned swx = (unsigned)lr << 4;

  f32x4 acc1[4];
#pragma unroll
  for (int mt = 0; mt < 4; ++mt) acc1[mt] = (f32x4){0.f, 0.f, 0.f, 0.f};
#pragma unroll
  for (int ks = 0; ks < 2; ++ks) {
    bf16x8 bh = *(const bf16x8*)(xs + ((col * 256 + ks * 64 + lg * 16) ^ swx));
    bf16x8 bl = *(const bf16x8*)(xs + ((col * 256 + 128 + ks * 64 + lg * 16) ^ swx));
#pragma unroll
    for (int mt = 0; mt < 4; ++mt) {
      int row = mt * 16 + lr;
      bf16x8 ah = *(const bf16x8*)(wbuf + ((row * 256 + ks * 64 + lg * 16) ^ swx));
      bf16x8 al = *(const bf16x8*)(wbuf + ((row * 256 + 128 + ks * 64 + lg * 16) ^ swx));
      acc1[mt] = __builtin_amdgcn_mfma_f32_16x16x32_bf16(ah, bh, acc1[mt], 0, 0, 0);
      acc1[mt] = __builtin_amdgcn_mfma_f32_16x16x32_bf16(ah, bl, acc1[mt], 0, 0, 0);
      acc1[mt] = __builtin_amdgcn_mfma_f32_16x16x32_bf16(al, bh, acc1[mt], 0, 0, 0);
    }
  }

  unsigned swg = (unsigned)(col & 7) << 4;
#pragma unroll
  for (int t = 0; t < 2; ++t) {
    float g0 = ftanh(acc1[t][0]) * ftanh(acc1[t + 2][0]);
    float g1 = ftanh(acc1[t][1]) * ftanh(acc1[t + 2][1]);
    float g2 = ftanh(acc1[t][2]) * ftanh(acc1[t + 2][2]);
    float g3 = ftanh(acc1[t][3]) * ftanh(acc1[t + 2][3]);
    unsigned long long lo01, lo23;
    unsigned long long hi01 = packhl2(g0, g1, &lo01);
    unsigned long long hi23 = packhl2(g2, g3, &lo23);
    int ob = (t * 16 + lg * 4) * 2;
    *(unsigned long long*)(gs + ((col * 128 + ob) ^ swg))      = hi01 | (hi23 << 32);
    *(unsigned long long*)(gs + ((col * 128 + 64 + ob) ^ swg)) = lo01 | (lo23 << 32);
  }

  f32x4 acc2[3];
  {
    bf16x8 bgh = *(const bf16x8*)(gs + ((col * 128 + lg * 16) ^ swg));
    bf16x8 bgl = *(const bf16x8*)(gs + ((col * 128 + 64 + lg * 16) ^ swg));
#pragma unroll
    for (int mt = 0; mt < 3; ++mt) {
      f32x4 z = {0.f, 0.f, 0.f, 0.f};
      z = __builtin_amdgcn_mfma_f32_16x16x32_bf16(a2h[mt], bgh, z, 0, 0, 0);
      z = __builtin_amdgcn_mfma_f32_16x16x32_bf16(a2h[mt], bgl, z, 0, 0, 0);
      acc2[mt] = __builtin_amdgcn_mfma_f32_16x16x32_bf16(a2l[mt], bgh, z, 0, 0, 0);
    }
  }

  int j = jb + col;
  if (writex && j < Tn) {
#pragma unroll
    for (int mt = 0; mt < 2; ++mt) {
      float4 v;
#pragma unroll
      for (int i = 0; i < 4; ++i) {
        int m = mt * 16 + lg * 4 + i;
        unsigned short xh = *(unsigned short*)(xs + ((col * 256 + 64 + m * 2) ^ swx));
        unsigned short xl = *(unsigned short*)(xs + ((col * 256 + 192 + m * 2) ^ swx));
        float r = acc2[mt][i] + (bf2f(xh) + bf2f(xl));
        if (i == 0) v.x = r; else if (i == 1) v.y = r; else if (i == 2) v.z = r; else v.w = r;
      }
      *(float4*)&xout[(size_t)j * 32 + mt * 16 + lg * 4] = v;
    }
  }
  int js = j - off_s;
  if (j < Tn && js >= 0) {
    float4 v = {acc2[2][0], acc2[2][1], acc2[2][2], acc2[2][3]};
    float* sp = skip + (size_t)js * 16 + lg * 4;
    if (first) {
      *(float4*)sp = v;
    } else {
      float4 o = *(const float4*)sp;
      o.x += v.x; o.y += v.y; o.z += v.z; o.w += v.w;
      *(float4*)sp = o;
    }
  }
}

// Fused final MLP, 32 cols/block: LDS 32KB -> ~5 blocks/CU, 4064 blocks.
// Waves 0,1: q-half 0 (q<128); waves 2,3: q-half 1. acco[8] static.
__global__ __launch_bounds__(256) void k_final(
    const float* __restrict__ skip,
    const unsigned short* __restrict__ w1p,
    const unsigned short* __restrict__ w2fp,
    float* __restrict__ out)
{
  __shared__ alignas(16) char smem[32768];
  char* sks = smem;             // [32 col][128B hi|lo] ^((col&7)<<4), 4KB
  char* w2s = smem;             // [256 q][64B hi] ^((q&7)<<4), 16KB (aliases sks)
  char* h1s = smem + 16384;     // [32 col][512B hi] ^(col<<4), 16KB
  float (*OutSq)[34] = (float (*)[34])&smem[0];  // [64][34] = 8704B (aliases w2s)

  int tid = threadIdx.x;
  int jb  = blockIdx.x * 32;
  int lane = tid & 63, w = tid >> 6;
  int lr = lane & 15, lg = lane >> 4;
  int col = (w & 1) * 16 + lr;
  int qh  = w >> 1;

  // skip staging: 32 cols (128 threads active), zero k>=16
  if (tid < 128) {
    int c = tid >> 2, k4 = (tid & 3) * 4;
    float4 v = *(const float4*)&skip[(size_t)(jb + c) * 16 + k4];
    v.x = fmaxf(v.x, 0.f); v.y = fmaxf(v.y, 0.f);
    v.z = fmaxf(v.z, 0.f); v.w = fmaxf(v.w, 0.f);
    unsigned long long lo01, lo23;
    unsigned long long hi01 = packhl2(v.x, v.y, &lo01);
    unsigned long long hi23 = packhl2(v.z, v.w, &lo23);
    unsigned sw = (unsigned)(c & 7) << 4;
    int base = c * 128 + k4 * 2;
    *(unsigned long long*)(sks + ((base) ^ sw))       = hi01 | (hi23 << 32);
    *(unsigned long long*)(sks + ((base + 64) ^ sw))  = lo01 | (lo23 << 32);
    *(unsigned long long*)(sks + ((base + 32) ^ sw))  = 0ull;
    *(unsigned long long*)(sks + ((base + 96) ^ sw))  = 0ull;
  }
  __syncthreads();

  unsigned swk = (unsigned)(col & 7) << 4;
  unsigned swh = (unsigned)col << 4;

  // GEMM1: this wave's col, q1-half qh (8 m-tiles)
  {
    bf16x8 bh = *(const bf16x8*)(sks + ((col * 128 + lg * 16) ^ swk));
    bf16x8 bl = *(const bf16x8*)(sks + ((col * 128 + 64 + lg * 16) ^ swk));
#pragma unroll
    for (int mt = 0; mt < 8; ++mt) {
      bf16x8 ah = {0, 0, 0, 0, 0, 0, 0, 0};
      bf16x8 al = {0, 0, 0, 0, 0, 0, 0, 0};
      if (lg < 2) {
        int m = qh * 128 + mt * 16 + lr;
        ah = *(const bf16x8*)(w1p + m * 32 + lg * 8);
        al = *(const bf16x8*)(w1p + m * 32 + 16 + lg * 8);
      }
      f32x4 z = {0.f, 0.f, 0.f, 0.f};
      z = __builtin_amdgcn_mfma_f32_16x16x32_bf16(ah, bh, z, 0, 0, 0);
      z = __builtin_amdgcn_mfma_f32_16x16x32_bf16(ah, bl, z, 0, 0, 0);
      z = __builtin_amdgcn_mfma_f32_16x16x32_bf16(al, bh, z, 0, 0, 0);
      int qb = (qh * 128 + mt * 16 + lg * 4) * 2;
      unsigned p01 = (unsigned)b16(fmaxf(z[0], 0.f)) | ((unsigned)b16(fmaxf(z[1], 0.f)) << 16);
      unsigned p23 = (unsigned)b16(fmaxf(z[2], 0.f)) | ((unsigned)b16(fmaxf(z[3], 0.f)) << 16);
      *(unsigned*)(h1s + ((col * 512 + qb) ^ swh))     = p01;
      *(unsigned*)(h1s + ((col * 512 + qb + 4) ^ swh)) = p23;
    }
  }

  // GEMM2: 8 chunks; W2 hi chunk staged into w2s (aliases sks)
  f32x4 acco[8];
#pragma unroll
  for (int mt = 0; mt < 8; ++mt) acco[mt] = (f32x4){0.f, 0.f, 0.f, 0.f};

  for (int kb = 0; kb < 8; ++kb) {
    __syncthreads();   // kb=0: GEMM1 sks reads + cross-wave h1 writes done; else prev w2s reads
    for (int i = tid; i < 1024; i += 256) {
      int q = i >> 2, part = i & 3;
      uint4 v = *(const uint4*)(w2fp + q * 512 + kb * 32 + part * 8);
      *(uint4*)(w2s + ((q * 64 + part * 16) ^ ((q & 7) << 4))) = v;
    }
    __syncthreads();
    bf16x8 bh = *(const bf16x8*)(h1s + ((col * 512 + kb * 64 + lg * 16) ^ swh));
#pragma unroll
    for (int mt = 0; mt < 8; ++mt) {
      int row = qh * 128 + mt * 16 + lr;
      bf16x8 ah = *(const bf16x8*)(w2s + ((row * 64 + lg * 16) ^ ((row & 7) << 4)));
      acco[mt] = __builtin_amdgcn_mfma_f32_16x16x32_bf16(ah, bh, acco[mt], 0, 0, 0);
    }
  }

  // epilogue: 4 passes of 64 q-rows through OutSq (full 128B-line stores)
#pragma unroll
  for (int p = 0; p < 4; ++p) {
    __syncthreads();   // prev pass reads (or last w2s reads) done
    if (qh == (p >> 1)) {
#pragma unroll
      for (int mq = 0; mq < 4; ++mq)
#pragma unroll
        for (int i = 0; i < 4; ++i)
          OutSq[mq * 16 + lg * 4 + i][col] = acco[(p & 1) * 4 + mq][i];
    }
    __syncthreads();
    int r = tid >> 2, cb = (tid & 3) * 8;
    size_t base = (size_t)(p * 64 + r) * TF + jb + cb;
    *(float4*)&out[base]     = *(float4*)&OutSq[r][cb];
    *(float4*)&out[base + 4] = *(float4*)&OutSq[r][cb + 4];
  }
}

extern "C" void kernel_launch(void* const* d_in, const int* in_sizes, int n_in,
                              void* d_out, int out_size, void* d_ws, size_t ws_size,
                              hipStream_t stream) {
  const float* x_in     = (const float*)d_in[0];
  const float* w_init   = (const float*)d_in[1];
  const float* w_filter = (const float*)d_in[2];
  const float* w_gate   = (const float*)d_in[3];
  const float* w_res    = (const float*)d_in[4];
  const float* w_skip   = (const float*)d_in[5];
  const float* w_f1     = (const float*)d_in[6];
  const float* w_f2     = (const float*)d_in[7];
  float* out = (float*)d_out;

  float* xa    = (float*)d_ws;                    // time-major [LBUF][32]
  float* xb    = xa + 32 * (size_t)LBUF;
  float* skipb = xb + 32 * (size_t)LBUF;          // time-major [TF][16]
  unsigned short* whp  = (unsigned short*)(skipb + 16 * (size_t)TF);
  unsigned short* w2p  = whp + 20 * 8192;
  unsigned short* w1p  = w2p + 20 * 3072;
  unsigned short* w2fp = w1p + 8192;

  k_pack<<<712, 256, 0, stream>>>(w_filter, w_gate, w_res, w_skip, w_f1, w_f2,
                                  whp, w2p, w1p, w2fp);

  int T = LBUF;
  for (int idx = 0; idx < 20; ++idx) {
    int d    = 1 << (idx % 10);
    int pad  = (d - (T % d)) % d;
    int Tn   = T + pad - d;
    int offs = Tn - TF;
    k_layer<<<(Tn + TB - 1) / TB, 256, 0, stream>>>(
        xa, xb, skipb,
        (const unsigned*)(whp + (size_t)idx * 8192), w2p + (size_t)idx * 3072,
        (idx == 0) ? x_in : nullptr, w_init,
        Tn, T, d, pad, offs, (idx == 0) ? 1 : 0, (idx == 19) ? 0 : 1);
    float* t = xa; xa = xb; xb = t;
    T = Tn;
  }

  k_final<<<TF / 32, 256, 0, stream>>>(skipb, w1p, w2fp, out);
}